// Round 2
// baseline (80.454 us; speedup 1.0000x reference)
//
#include <hip/hip_runtime.h>

// Bilinear flow warp: images [32,3,512,512] f32, flows [32,2,512,512] f32
// flows[:,0] perturbs y (rows), flows[:,1] perturbs x (cols).
// out[b,c,h,w] = bilinear(images[b,c], y=h+fy clamped, x=w+fx clamped)
//
// Mapping: ONE pixel per thread, consecutive lanes = consecutive x.
// Rationale (R1 post-mortem): with 4 consecutive pixels/thread, each gather
// instruction spanned ~16 cache lines/wave (lanes stride 16B) -> L1 address
// processing bound (~43us of line events), HBM only 66% utilized. With
// lane-consecutive pixels each gather spans ~2-3 lines -> VMEM pipe freed.

__global__ __launch_bounds__(256) void warp_bilinear(
    const float* __restrict__ images,
    const float* __restrict__ flows,
    float* __restrict__ out)
{
    constexpr int C = 3, H = 512, W = 512;
    constexpr int HW = H * W;

    int idx = blockIdx.x * blockDim.x + threadIdx.x;   // flat pixel in B*H*W
    int b  = idx >> 18;          // / HW   (HW = 2^18)
    int hw = idx & (HW - 1);
    int h  = hw >> 9;            // / W
    int w  = hw & (W - 1);

    // flow loads: coalesced dword per lane; nontemporal (streamed once)
    const float* flow_b = flows + (size_t)b * 2 * HW + hw;
    float fy = __builtin_nontemporal_load(flow_b);        // channel 0 = dy
    float fx = __builtin_nontemporal_load(flow_b + HW);   // channel 1 = dx

    float sx = fminf(fmaxf((float)w + fx, 0.0f), (float)(W - 1));
    float sy = fminf(fmaxf((float)h + fy, 0.0f), (float)(H - 1));
    int x0 = min((int)sx, W - 2);   // sx >= 0, so (int) == floor
    int y0 = min((int)sy, H - 2);
    float dx = sx - (float)x0;
    float dy = sy - (float)y0;
    float wa = (1.0f - dx) * (1.0f - dy);  // (y0,x0)
    float wb = (1.0f - dx) * dy;           // (y1,x0)
    float wc = dx * (1.0f - dy);           // (y0,x1)
    float wd = dx * dy;                    // (y1,x1)

    const float* img = images + (size_t)b * C * HW + y0 * W + x0;

    float r[C];
#pragma unroll
    for (int c = 0; c < C; ++c) {
        const float* base = img + c * HW;
        float Ia = base[0];
        float Ic = base[1];
        float Ib = base[W];
        float Id = base[W + 1];
        r[c] = wa * Ia + wb * Ib + wc * Ic + wd * Id;
    }

    float* outp = out + (size_t)b * C * HW + hw;
#pragma unroll
    for (int c = 0; c < C; ++c)
        __builtin_nontemporal_store(r[c], outp + c * HW);
}

extern "C" void kernel_launch(void* const* d_in, const int* in_sizes, int n_in,
                              void* d_out, int out_size, void* d_ws, size_t ws_size,
                              hipStream_t stream) {
    const float* images = (const float*)d_in[0];
    const float* flows  = (const float*)d_in[1];
    float* out = (float*)d_out;

    constexpr int B = 32, H = 512, W = 512;
    constexpr int total = B * H * W;               // 8,388,608 pixels
    dim3 block(256);
    dim3 grid(total / 256);                        // 32768 blocks
    hipLaunchKernelGGL(warp_bilinear, grid, block, 0, stream, images, flows, out);
}